// Round 2
// baseline (814.593 us; speedup 1.0000x reference)
//
#include <hip/hip_runtime.h>
#include <stdint.h>

// LocalAttentionBlock: x[4,2048,2048] -> out[4,2048,2048] fp32
// Pipeline: cvt -> fused QKV GEMM (bf16 MFMA) -> RoPE/scatter -> flash attn v2 -> out GEMM (+bias)

#define WIDTH_ 2048
#define NHEADS_ 16
#define HD_ 128
#define WINDOW_ 1024
#define B_ 4
#define T_ 2048
#define MROWS_ (B_ * T_)          // 8192
#define NQKV_ (WIDTH_ + 2 * HD_)  // 2304

typedef float f32x4 __attribute__((ext_vector_type(4)));
typedef __bf16 bf16x8 __attribute__((ext_vector_type(8)));
typedef float f32x4v __attribute__((ext_vector_type(4)));
typedef unsigned short u16;
typedef unsigned int u32;

__device__ __forceinline__ u16 f2bf(float x) {
  u32 u = __builtin_bit_cast(u32, x);
  return (u16)((u + 0x7FFFu + ((u >> 16) & 1u)) >> 16);  // RNE
}
__device__ __forceinline__ float bf2f(u16 b) {
  u32 u = ((u32)b) << 16;
  return __builtin_bit_cast(float, u);
}
__device__ __forceinline__ u32 pack2bf(float a, float b) {
  // let the compiler emit v_cvt (HW RNE); don't hand-write cvt_pk (m240)
  union { __bf16 h[2]; u32 u; } c;
  c.h[0] = (__bf16)a; c.h[1] = (__bf16)b;
  return c.u;
}

__device__ __forceinline__ f32x4 mfma16(bf16x8 a, bf16x8 b, f32x4 c) {
  return __builtin_amdgcn_mfma_f32_16x16x32_bf16(a, b, c, 0, 0, 0);
}

#define GLL16(gp, lp)                                          \
  __builtin_amdgcn_global_load_lds(                            \
      (const __attribute__((address_space(1))) void*)(gp),     \
      (__attribute__((address_space(3))) void*)(lp), 16, 0, 0)

// ---------------- fp32 -> bf16 convert (vectorized) ----------------
__global__ __launch_bounds__(256) void cvt_f32_bf16(const float* __restrict__ src,
                                                    u16* __restrict__ dst, int n4) {
  int i = blockIdx.x * blockDim.x + threadIdx.x;
  int stride = gridDim.x * blockDim.x;
  for (; i < n4; i += stride) {
    f32x4v v = *reinterpret_cast<const f32x4v*>(src + 4 * (size_t)i);
    u32 lo = (u32)f2bf(v[0]) | ((u32)f2bf(v[1]) << 16);
    u32 hi = (u32)f2bf(v[2]) | ((u32)f2bf(v[3]) << 16);
    uint2 o;
    o.x = lo; o.y = hi;
    *reinterpret_cast<uint2*>(dst + 4 * (size_t)i) = o;
  }
}

// ---------------- GEMM: C[M,N] = A[M,K] * W[N,K]^T (+bias) ----------------
// 128x128 tile, BK=32, 4 waves (2x2 of 64x64), 16x16x32 bf16 MFMA, global_load_lds staging.
template <bool F32OUT>
__global__ __launch_bounds__(256) void gemm_bt(const u16* __restrict__ A,
                                               const u16* __restrict__ W,
                                               void* __restrict__ Cout,
                                               const float* __restrict__ bias,
                                               int M, int N, int K) {
  __shared__ alignas(16) u16 As[128 * 32];
  __shared__ alignas(16) u16 Bs[128 * 32];
  const int tid = threadIdx.x;
  const int wid = tid >> 6, lane = tid & 63;
  const int g = lane >> 4, lr = lane & 15;
  const int m0 = blockIdx.y << 7, n0 = blockIdx.x << 7;
  const int wm = wid >> 1, wn = wid & 1;

  const f32x4 vzero = {0.f, 0.f, 0.f, 0.f};
  f32x4 acc[4][4];
#pragma unroll
  for (int i = 0; i < 4; i++)
#pragma unroll
    for (int j = 0; j < 4; j++) acc[i][j] = vzero;

  const int c0 = wid * 2, c1 = wid * 2 + 1;
  const int lrow = lane >> 2;
  const int lcol = (lane & 3) * 8;
  const u16* a0 = A + (size_t)(m0 + c0 * 16 + lrow) * K + lcol;
  const u16* a1 = A + (size_t)(m0 + c1 * 16 + lrow) * K + lcol;
  const u16* b0 = W + (size_t)(n0 + c0 * 16 + lrow) * K + lcol;
  const u16* b1 = W + (size_t)(n0 + c1 * 16 + lrow) * K + lcol;

  for (int k0 = 0; k0 < K; k0 += 32) {
    __syncthreads();
    GLL16(a0 + k0, &As[c0 * 512]);
    GLL16(a1 + k0, &As[c1 * 512]);
    GLL16(b0 + k0, &Bs[c0 * 512]);
    GLL16(b1 + k0, &Bs[c1 * 512]);
    __syncthreads();

    bf16x8 af[4], bfv[4];
#pragma unroll
    for (int mi = 0; mi < 4; mi++)
      af[mi] = *(const bf16x8*)&As[(wm * 64 + mi * 16 + lr) * 32 + g * 8];
#pragma unroll
    for (int ni = 0; ni < 4; ni++)
      bfv[ni] = *(const bf16x8*)&Bs[(wn * 64 + ni * 16 + lr) * 32 + g * 8];
#pragma unroll
    for (int mi = 0; mi < 4; mi++)
#pragma unroll
      for (int ni = 0; ni < 4; ni++)
        acc[mi][ni] = mfma16(af[mi], bfv[ni], acc[mi][ni]);
  }

#pragma unroll
  for (int mi = 0; mi < 4; mi++) {
    int row = m0 + wm * 64 + mi * 16 + g * 4;
#pragma unroll
    for (int ni = 0; ni < 4; ni++) {
      int col = n0 + wn * 64 + ni * 16 + lr;
#pragma unroll
      for (int r = 0; r < 4; r++) {
        float v = acc[mi][ni][r];
        if (F32OUT) {
          ((float*)Cout)[(size_t)(row + r) * N + col] = v + bias[col];
        } else {
          ((u16*)Cout)[(size_t)(row + r) * N + col] = f2bf(v);
        }
      }
    }
  }
}

// ---------------- RoPE + scatter ----------------
__global__ __launch_bounds__(256) void rope_scatter(const u16* __restrict__ QKV,
                                                    const int* __restrict__ segpos,
                                                    u16* __restrict__ Qb,
                                                    u16* __restrict__ Kb,
                                                    u16* __restrict__ VT) {
  const int row = blockIdx.x;  // b*T + t
  const int b = row / T_, t = row % T_;
  const float pos = (float)segpos[t];
  const u16* src = QKV + (size_t)row * NQKV_;
  const int tid = threadIdx.x;
  const float L2_10K_OVER_32 = 0.4152410118609203f;  // log2(10000)/32

  for (int j = tid; j < NHEADS_ * 32; j += 256) {
    int h = j >> 5, d = j & 31;
    float inv = exp2f(-(float)d * L2_10K_OVER_32);
    float ang = pos * inv;
    float sn = sinf(ang), cs = cosf(ang);
    int c1 = h * HD_ + d, c2 = c1 + 32;
    float x1 = bf2f(src[c1]), x2 = bf2f(src[c2]);
    Qb[(size_t)row * WIDTH_ + c1] = f2bf(x1 * cs - x2 * sn);
    Qb[(size_t)row * WIDTH_ + c2] = f2bf(x2 * cs + x1 * sn);
  }
  for (int j = tid; j < NHEADS_ * 64; j += 256) {
    int h = j >> 6, d = j & 63;
    int c = h * HD_ + 64 + d;
    Qb[(size_t)row * WIDTH_ + c] = src[c];
  }
  if (tid < 32) {
    int d = tid;
    float inv = exp2f(-(float)d * L2_10K_OVER_32);
    float ang = pos * inv;
    float sn = sinf(ang), cs = cosf(ang);
    float x1 = bf2f(src[WIDTH_ + d]), x2 = bf2f(src[WIDTH_ + d + 32]);
    Kb[(size_t)row * HD_ + d] = f2bf(x1 * cs - x2 * sn);
    Kb[(size_t)row * HD_ + d + 32] = f2bf(x2 * cs + x1 * sn);
  } else if (tid >= 64 && tid < 128) {
    int d = tid;
    Kb[(size_t)row * HD_ + d] = src[WIDTH_ + d];
  }
  for (int j = tid; j < HD_; j += 256) {
    VT[((size_t)b * HD_ + j) * T_ + t] = src[WIDTH_ + HD_ + j];
  }
}

// ---------------- Flash attention v2 (MQA, causal + window) ----------------
// 1 wave per 16 q-rows, s-tiles of 64. Swapped QK^T (mfma(K,Q)) => lane owns one
// q-row's P values => lane-parallel softmax (2 shfl). P transposed via XOR-swizzled
// per-wave LDS. Interior tiles skip masking; defer-max skips rescale (THR=8).
__global__ __launch_bounds__(256) void attn(const u16* __restrict__ Qb,
                                            const u16* __restrict__ Kb,
                                            const u16* __restrict__ VT,
                                            u16* __restrict__ Eb) {
  const int tid = threadIdx.x;
  const int wid = tid >> 6, lane = tid & 63;
  const int g = lane >> 4, lr = lane & 15;
  const int nt64 = T_ / 64;  // 32
  const int qt = blockIdx.x % nt64;
  const int n = (blockIdx.x / nt64) % NHEADS_;
  const int b = blockIdx.x / (nt64 * NHEADS_);
  const int q0 = qt * 64 + wid * 16;

  // per-wave P buffer: [16 q][64 s] bf16, XOR-swizzled (byte ^= (q&7)<<4)
  __shared__ alignas(16) u16 Pl[4][16 * 64];
  char* P = (char*)Pl[wid];
  const int swz = (lr & 7) << 4;

  // Q B-frags: lane holds Q[q0+lr][kk*32 + g*8 .. +8]
  bf16x8 qf[4];
  {
    const u16* qrow = Qb + (size_t)(b * T_ + q0 + lr) * WIDTH_ + n * HD_;
#pragma unroll
    for (int kk = 0; kk < 4; kk++) qf[kk] = *(const bf16x8*)(qrow + kk * 32 + g * 8);
  }

  const f32x4 vzero = {0.f, 0.f, 0.f, 0.f};
  f32x4 eacc[8];
#pragma unroll
  for (int i = 0; i < 8; i++) eacc[i] = vzero;
  float m_r = -1e30f, l_r = 0.f;  // per-lane: q = q0 + lr

  const u16* kbase = Kb + (size_t)b * T_ * HD_;
  const u16* vbase = VT + (size_t)b * HD_ * T_;
  const float CSC = 0.08838834764831845f * 1.4426950408889634f;  // 128^-0.5 * log2(e)
  const int q = q0 + lr;

  const int s_begin = (q0 > WINDOW_) ? ((q0 - WINDOW_) & ~63) : 0;
  const int s_end = q0 + 15;  // inclusive

  for (int s0 = s_begin; s0 <= s_end; s0 += 64) {
    // ---- QK^T swapped: S[64 s x 16 q]; lane holds s = s0+h*16+g*4+r for q=q0+lr ----
    f32x4 sacc[4];
#pragma unroll
    for (int h = 0; h < 4; h++) sacc[h] = vzero;
#pragma unroll
    for (int h = 0; h < 4; h++) {
      const u16* krow = kbase + (size_t)(s0 + h * 16 + lr) * HD_;
#pragma unroll
      for (int kk = 0; kk < 4; kk++) {
        bf16x8 kf = *(const bf16x8*)(krow + kk * 32 + g * 8);
        sacc[h] = mfma16(kf, qf[kk], sacc[h]);
      }
    }

    // ---- mask + scale; row max (lane-parallel) ----
    const bool interior = (s0 + 63 <= q0) && (s0 >= q0 + 15 - WINDOW_);
    float pv[4][4];
    float pmax = -1e30f;
    if (interior) {
#pragma unroll
      for (int h = 0; h < 4; h++)
#pragma unroll
        for (int r = 0; r < 4; r++) {
          float v = sacc[h][r] * CSC;
          pv[h][r] = v;
          pmax = fmaxf(pmax, v);
        }
    } else {
#pragma unroll
      for (int h = 0; h < 4; h++)
#pragma unroll
        for (int r = 0; r < 4; r++) {
          int s = s0 + h * 16 + g * 4 + r;
          bool val = (s <= q) && (s + WINDOW_ >= q);
          float v = val ? sacc[h][r] * CSC : -1e30f;
          pv[h][r] = v;
          pmax = fmaxf(pmax, v);
        }
    }
    pmax = fmaxf(pmax, __shfl_xor(pmax, 16));
    pmax = fmaxf(pmax, __shfl_xor(pmax, 32));

    // ---- online softmax with defer-max (THR=8) ----
    if (!__all(pmax <= m_r + 8.f)) {
      float mnew = fmaxf(m_r, pmax);
      float alpha = exp2f(m_r - mnew);
      m_r = mnew;
      l_r *= alpha;
      float aq[4];
#pragma unroll
      for (int r = 0; r < 4; r++) aq[r] = __shfl(alpha, g * 4 + r);
#pragma unroll
      for (int i = 0; i < 8; i++) {
        f32x4 e = eacc[i];
#pragma unroll
        for (int r = 0; r < 4; r++) e[r] *= aq[r];
        eacc[i] = e;
      }
    }
    float rs = 0.f;
#pragma unroll
    for (int h = 0; h < 4; h++)
#pragma unroll
      for (int r = 0; r < 4; r++) {
        float e = exp2f(pv[h][r] - m_r);
        pv[h][r] = e;
        rs += e;
      }
    rs += __shfl_xor(rs, 16);
    rs += __shfl_xor(rs, 32);
    l_r += rs;

    // ---- P -> LDS (bf16, [q][s], swizzled write) ----
#pragma unroll
    for (int h = 0; h < 4; h++) {
      int base = (lr * 128 + h * 32 + g * 8) ^ swz;
      *(u32*)(P + base) = pack2bf(pv[h][0], pv[h][1]);
      *(u32*)(P + base + 4) = pack2bf(pv[h][2], pv[h][3]);
    }
    // A-frags: P[q=lr][kk*32 + g*8 ..] (swizzled read, same XOR)
    bf16x8 pf0 = *(const bf16x8*)(P + ((lr * 128 + g * 16) ^ swz));
    bf16x8 pf1 = *(const bf16x8*)(P + ((lr * 128 + 64 + g * 16) ^ swz));

    // ---- PV: eacc[ht] (C[q][d]) += P[q][s] * VT[d][s] ----
#pragma unroll
    for (int ht = 0; ht < 8; ht++) {
      const u16* vrow = vbase + (size_t)(ht * 16 + lr) * T_ + s0 + g * 8;
      bf16x8 vf0 = *(const bf16x8*)vrow;
      bf16x8 vf1 = *(const bf16x8*)(vrow + 32);
      eacc[ht] = mfma16(pf0, vf0, eacc[ht]);
      eacc[ht] = mfma16(pf1, vf1, eacc[ht]);
    }
  }

  // ---- normalize + store encoded (q = q0 + g*4 + r, d = ht*16 + lr) ----
  float lq[4];
#pragma unroll
  for (int r = 0; r < 4; r++) lq[r] = 1.f / __shfl(l_r, g * 4 + r);
#pragma unroll
  for (int ht = 0; ht < 8; ht++) {
#pragma unroll
    for (int r = 0; r < 4; r++) {
      int row = b * T_ + q0 + g * 4 + r;
      int col = n * HD_ + ht * 16 + lr;
      Eb[(size_t)row * WIDTH_ + col] = f2bf(eacc[ht][r] * lq[r]);
    }
  }
}

// ---------------- launch ----------------
extern "C" void kernel_launch(void* const* d_in, const int* in_sizes, int n_in,
                              void* d_out, int out_size, void* d_ws, size_t ws_size,
                              hipStream_t stream) {
  (void)in_sizes; (void)n_in; (void)out_size; (void)ws_size;
  const float* x = (const float*)d_in[0];
  const int* segpos = (const int*)d_in[1];
  const float* wq = (const float*)d_in[3];
  const float* wk = (const float*)d_in[4];
  const float* wv = (const float*)d_in[5];
  const float* w_out = (const float*)d_in[6];
  const float* b_out = (const float*)d_in[7];

  char* p = (char*)d_ws;
  u16* xb = (u16*)p;   p += (size_t)MROWS_ * WIDTH_ * 2;
  u16* wqkv = (u16*)p; p += (size_t)NQKV_ * WIDTH_ * 2;
  u16* wob = (u16*)p;  p += (size_t)WIDTH_ * WIDTH_ * 2;
  u16* qkv = (u16*)p;  p += (size_t)MROWS_ * NQKV_ * 2;
  u16* qb = (u16*)p;   p += (size_t)MROWS_ * WIDTH_ * 2;
  u16* kb = (u16*)p;   p += (size_t)MROWS_ * HD_ * 2;
  u16* vt = (u16*)p;   p += (size_t)B_ * HD_ * T_ * 2;
  u16* eb = xb;  // alias: xb dead after QKV GEMM

  cvt_f32_bf16<<<4096, 256, 0, stream>>>(x, xb, MROWS_ * WIDTH_ / 4);
  cvt_f32_bf16<<<1024, 256, 0, stream>>>(wq, wqkv, WIDTH_ * WIDTH_ / 4);
  cvt_f32_bf16<<<256, 256, 0, stream>>>(wk, wqkv + (size_t)WIDTH_ * WIDTH_, HD_ * WIDTH_ / 4);
  cvt_f32_bf16<<<256, 256, 0, stream>>>(wv, wqkv + (size_t)(WIDTH_ + HD_) * WIDTH_, HD_ * WIDTH_ / 4);
  cvt_f32_bf16<<<1024, 256, 0, stream>>>(w_out, wob, WIDTH_ * WIDTH_ / 4);

  gemm_bt<false><<<dim3(NQKV_ / 128, MROWS_ / 128), 256, 0, stream>>>(
      xb, wqkv, qkv, nullptr, MROWS_, NQKV_, WIDTH_);
  rope_scatter<<<MROWS_, 256, 0, stream>>>(qkv, segpos, qb, kb, vt);
  attn<<<B_ * NHEADS_ * (T_ / 64), 256, 0, stream>>>(qb, kb, vt, eb);
  gemm_bt<true><<<dim3(WIDTH_ / 128, MROWS_ / 128), 256, 0, stream>>>(
      eb, wob, d_out, b_out, MROWS_, WIDTH_, WIDTH_);
}

// Round 3
// 393.672 us; speedup vs baseline: 2.0692x; 2.0692x over previous
//
#include <hip/hip_runtime.h>
#include <stdint.h>

// LocalAttentionBlock: x[4,2048,2048] -> out[4,2048,2048] fp32
// cvt -> fused QKV GEMM (bf16 MFMA) -> RoPE/scatter -> flash attn v3 (LDS-staged, dbuf) -> out GEMM

#define WIDTH_ 2048
#define NHEADS_ 16
#define HD_ 128
#define WINDOW_ 1024
#define B_ 4
#define T_ 2048
#define MROWS_ (B_ * T_)          // 8192
#define NQKV_ (WIDTH_ + 2 * HD_)  // 2304

typedef float f32x4 __attribute__((ext_vector_type(4)));
typedef __bf16 bf16x8 __attribute__((ext_vector_type(8)));
typedef float f32x4v __attribute__((ext_vector_type(4)));
typedef unsigned short u16;
typedef unsigned int u32;

__device__ __forceinline__ u16 f2bf(float x) {
  u32 u = __builtin_bit_cast(u32, x);
  return (u16)((u + 0x7FFFu + ((u >> 16) & 1u)) >> 16);  // RNE
}
__device__ __forceinline__ float bf2f(u16 b) {
  u32 u = ((u32)b) << 16;
  return __builtin_bit_cast(float, u);
}
__device__ __forceinline__ u32 pack2bf(float a, float b) {
  union { __bf16 h[2]; u32 u; } c;
  c.h[0] = (__bf16)a; c.h[1] = (__bf16)b;
  return c.u;
}

__device__ __forceinline__ f32x4 mfma16(bf16x8 a, bf16x8 b, f32x4 c) {
  return __builtin_amdgcn_mfma_f32_16x16x32_bf16(a, b, c, 0, 0, 0);
}

#define GLL16(gp, lp)                                          \
  __builtin_amdgcn_global_load_lds(                            \
      (const __attribute__((address_space(1))) void*)(gp),     \
      (__attribute__((address_space(3))) void*)(lp), 16, 0, 0)

// ---------------- fp32 -> bf16 convert ----------------
__global__ __launch_bounds__(256) void cvt_f32_bf16(const float* __restrict__ src,
                                                    u16* __restrict__ dst, int n4) {
  int i = blockIdx.x * blockDim.x + threadIdx.x;
  int stride = gridDim.x * blockDim.x;
  for (; i < n4; i += stride) {
    f32x4v v = *reinterpret_cast<const f32x4v*>(src + 4 * (size_t)i);
    u32 lo = (u32)f2bf(v[0]) | ((u32)f2bf(v[1]) << 16);
    u32 hi = (u32)f2bf(v[2]) | ((u32)f2bf(v[3]) << 16);
    uint2 o;
    o.x = lo; o.y = hi;
    *reinterpret_cast<uint2*>(dst + 4 * (size_t)i) = o;
  }
}

// ---------------- GEMM: C[M,N] = A[M,K] * W[N,K]^T (+bias) ----------------
template <bool F32OUT>
__global__ __launch_bounds__(256) void gemm_bt(const u16* __restrict__ A,
                                               const u16* __restrict__ W,
                                               void* __restrict__ Cout,
                                               const float* __restrict__ bias,
                                               int M, int N, int K) {
  __shared__ alignas(16) u16 As[128 * 32];
  __shared__ alignas(16) u16 Bs[128 * 32];
  const int tid = threadIdx.x;
  const int wid = tid >> 6, lane = tid & 63;
  const int g = lane >> 4, lr = lane & 15;
  const int m0 = blockIdx.y << 7, n0 = blockIdx.x << 7;
  const int wm = wid >> 1, wn = wid & 1;

  const f32x4 vzero = {0.f, 0.f, 0.f, 0.f};
  f32x4 acc[4][4];
#pragma unroll
  for (int i = 0; i < 4; i++)
#pragma unroll
    for (int j = 0; j < 4; j++) acc[i][j] = vzero;

  const int c0 = wid * 2, c1 = wid * 2 + 1;
  const int lrow = lane >> 2;
  const int lcol = (lane & 3) * 8;
  const u16* a0 = A + (size_t)(m0 + c0 * 16 + lrow) * K + lcol;
  const u16* a1 = A + (size_t)(m0 + c1 * 16 + lrow) * K + lcol;
  const u16* b0 = W + (size_t)(n0 + c0 * 16 + lrow) * K + lcol;
  const u16* b1 = W + (size_t)(n0 + c1 * 16 + lrow) * K + lcol;

  for (int k0 = 0; k0 < K; k0 += 32) {
    __syncthreads();
    GLL16(a0 + k0, &As[c0 * 512]);
    GLL16(a1 + k0, &As[c1 * 512]);
    GLL16(b0 + k0, &Bs[c0 * 512]);
    GLL16(b1 + k0, &Bs[c1 * 512]);
    __syncthreads();

    bf16x8 af[4], bfv[4];
#pragma unroll
    for (int mi = 0; mi < 4; mi++)
      af[mi] = *(const bf16x8*)&As[(wm * 64 + mi * 16 + lr) * 32 + g * 8];
#pragma unroll
    for (int ni = 0; ni < 4; ni++)
      bfv[ni] = *(const bf16x8*)&Bs[(wn * 64 + ni * 16 + lr) * 32 + g * 8];
#pragma unroll
    for (int mi = 0; mi < 4; mi++)
#pragma unroll
      for (int ni = 0; ni < 4; ni++)
        acc[mi][ni] = mfma16(af[mi], bfv[ni], acc[mi][ni]);
  }

#pragma unroll
  for (int mi = 0; mi < 4; mi++) {
    int row = m0 + wm * 64 + mi * 16 + g * 4;
#pragma unroll
    for (int ni = 0; ni < 4; ni++) {
      int col = n0 + wn * 64 + ni * 16 + lr;
#pragma unroll
      for (int r = 0; r < 4; r++) {
        float v = acc[mi][ni][r];
        if (F32OUT) {
          ((float*)Cout)[(size_t)(row + r) * N + col] = v + bias[col];
        } else {
          ((u16*)Cout)[(size_t)(row + r) * N + col] = f2bf(v);
        }
      }
    }
  }
}

// ---------------- RoPE + scatter ----------------
__global__ __launch_bounds__(256) void rope_scatter(const u16* __restrict__ QKV,
                                                    const int* __restrict__ segpos,
                                                    u16* __restrict__ Qb,
                                                    u16* __restrict__ Kb,
                                                    u16* __restrict__ VT) {
  const int row = blockIdx.x;  // b*T + t
  const int b = row / T_, t = row % T_;
  const float pos = (float)segpos[t];
  const u16* src = QKV + (size_t)row * NQKV_;
  const int tid = threadIdx.x;
  const float L2_10K_OVER_32 = 0.4152410118609203f;  // log2(10000)/32

  for (int j = tid; j < NHEADS_ * 32; j += 256) {
    int h = j >> 5, d = j & 31;
    float inv = exp2f(-(float)d * L2_10K_OVER_32);
    float ang = pos * inv;
    float sn = sinf(ang), cs = cosf(ang);
    int c1 = h * HD_ + d, c2 = c1 + 32;
    float x1 = bf2f(src[c1]), x2 = bf2f(src[c2]);
    Qb[(size_t)row * WIDTH_ + c1] = f2bf(x1 * cs - x2 * sn);
    Qb[(size_t)row * WIDTH_ + c2] = f2bf(x2 * cs + x1 * sn);
  }
  for (int j = tid; j < NHEADS_ * 64; j += 256) {
    int h = j >> 6, d = j & 63;
    int c = h * HD_ + 64 + d;
    Qb[(size_t)row * WIDTH_ + c] = src[c];
  }
  if (tid < 32) {
    int d = tid;
    float inv = exp2f(-(float)d * L2_10K_OVER_32);
    float ang = pos * inv;
    float sn = sinf(ang), cs = cosf(ang);
    float x1 = bf2f(src[WIDTH_ + d]), x2 = bf2f(src[WIDTH_ + d + 32]);
    Kb[(size_t)row * HD_ + d] = f2bf(x1 * cs - x2 * sn);
    Kb[(size_t)row * HD_ + d + 32] = f2bf(x2 * cs + x1 * sn);
  } else if (tid >= 64 && tid < 128) {
    int d = tid;
    Kb[(size_t)row * HD_ + d] = src[WIDTH_ + d];
  }
  for (int j = tid; j < HD_; j += 256) {
    VT[((size_t)b * HD_ + j) * T_ + t] = src[WIDTH_ + HD_ + j];
  }
}

// ---------------- Flash attention v3 ----------------
// Block: 128 q rows x 1 head, 4 waves x 32 q rows (2 subtiles of 16).
// K/V staged in double-buffered LDS via global_load_lds (XOR-swizzled source),
// one barrier per 64-s tile; swapped QK^T, lane-parallel softmax, P via LDS.
__global__ __launch_bounds__(256, 2) void attn(const u16* __restrict__ Qb,
                                               const u16* __restrict__ Kb,
                                               const u16* __restrict__ VT,
                                               u16* __restrict__ Eb) {
  __shared__ alignas(16) u16 Ks[2][64 * 128];   // [s][d], swizzled rows (256B)
  __shared__ alignas(16) u16 Vs[2][128 * 64];   // [d][s], swizzled rows (128B)
  __shared__ alignas(16) u16 Ps[4][2][16 * 64]; // per-wave, per-subtile

  const int tid = threadIdx.x;
  const int wid = tid >> 6, lane = tid & 63;
  const int g = lane >> 4, lr = lane & 15;
  const int nqt = T_ / 128;  // 16
  const int qt = blockIdx.x % nqt;
  const int n = (blockIdx.x / nqt) % NHEADS_;
  const int b = blockIdx.x / (nqt * NHEADS_);
  const int q0b = qt * 128;
  const int q0w = q0b + wid * 32;

  const char* kptr = (const char*)(Kb + (size_t)b * T_ * HD_);
  const char* vptr = (const char*)(VT + (size_t)b * HD_ * T_);

  // per-lane staging source bases (s0-invariant); wave 0,1 -> K; wave 2,3 -> V
  const char* srcb[8];
  int smul;
  if (wid < 2) {
    smul = HD_ * 2;  // bytes per s row
#pragma unroll
    for (int i = 0; i < 8; i++) {
      int row = wid * 32 + i * 4 + (lane >> 4);
      int c = (lane & 15) << 4;
      srcb[i] = kptr + (size_t)row * 256 + (c ^ ((row & 7) << 4));
    }
  } else {
    smul = 2;  // bytes per s col
#pragma unroll
    for (int i = 0; i < 8; i++) {
      int row = (wid - 2) * 64 + i * 8 + (lane >> 3);
      int c = (lane & 7) << 4;
      srcb[i] = vptr + (size_t)row * (T_ * 2) + (c ^ ((row & 7) << 4));
    }
  }

  // Q fragments: qf[su][kk] = Q[q0w+su*16+lr][n*HD + kk*32 + g*8 ..]
  bf16x8 qf[2][4];
#pragma unroll
  for (int su = 0; su < 2; su++) {
    const u16* qrow = Qb + (size_t)(b * T_ + q0w + su * 16 + lr) * WIDTH_ + n * HD_;
#pragma unroll
    for (int kk = 0; kk < 4; kk++) qf[su][kk] = *(const bf16x8*)(qrow + kk * 32 + g * 8);
  }

  const f32x4 vzero = {0.f, 0.f, 0.f, 0.f};
  f32x4 eacc[2][8];
#pragma unroll
  for (int su = 0; su < 2; su++)
#pragma unroll
    for (int i = 0; i < 8; i++) eacc[su][i] = vzero;
  float m_r[2] = {-1e30f, -1e30f}, l_r[2] = {0.f, 0.f};

  const float CSC = 0.08838834764831845f * 1.4426950408889634f;  // 128^-0.5 * log2(e)
  const int sbeg = (q0b > WINDOW_) ? (q0b - WINDOW_) : 0;
  const int nt = (q0b + 127 - sbeg) / 64 + 1;

  char* Pw = (char*)Ps[wid];
  const int swz = (lr & 7) << 4;

  // ---- stage tile helper ----
  auto STAGE = [&](int s0, int buf) {
    char* dbase = (wid < 2) ? ((char*)Ks[buf] + wid * 8192)
                            : ((char*)Vs[buf] + (wid - 2) * 8192);
#pragma unroll
    for (int i = 0; i < 8; i++) {
      GLL16(srcb[i] + (size_t)s0 * smul, dbase + i * 1024);
    }
  };

  STAGE(sbeg, 0);
  __syncthreads();

  for (int t = 0; t < nt; ++t) {
    const int s0 = sbeg + t * 64;
    const int cur = t & 1;
    if (t + 1 < nt) STAGE(s0 + 64, cur ^ 1);

    const bool active = (s0 <= q0w + 31) && (s0 + 63 >= q0w - WINDOW_);
    if (active) {
      const char* kB = (const char*)Ks[cur];
      const char* vB = (const char*)Vs[cur];
      // ---- QK^T: sacc[su][h][r] = S[s0+h*16+g*4+r][q0w+su*16+lr] ----
      f32x4 sacc[2][4];
#pragma unroll
      for (int su = 0; su < 2; su++)
#pragma unroll
        for (int h = 0; h < 4; h++) sacc[su][h] = vzero;
#pragma unroll
      for (int h = 0; h < 4; h++) {
        bf16x8 kf[4];
        const int krow = h * 16 + lr;
#pragma unroll
        for (int kk = 0; kk < 4; kk++)
          kf[kk] = *(const bf16x8*)(kB + krow * 256 + ((kk * 64 + g * 16) ^ swz));
#pragma unroll
        for (int su = 0; su < 2; su++)
#pragma unroll
          for (int kk = 0; kk < 4; kk++)
            sacc[su][h] = mfma16(kf[kk], qf[su][kk], sacc[su][h]);
      }

      // ---- softmax per subtile ----
      const bool wint = (s0 + 63 <= q0w) && (s0 >= q0w + 31 - WINDOW_);
#pragma unroll
      for (int su = 0; su < 2; su++) {
        const int qq = q0w + su * 16 + lr;
        float pm = -1e30f;
        if (wint) {
#pragma unroll
          for (int h = 0; h < 4; h++)
#pragma unroll
            for (int r = 0; r < 4; r++) {
              float v = sacc[su][h][r] * CSC;
              sacc[su][h][r] = v;
              pm = fmaxf(pm, v);
            }
        } else {
#pragma unroll
          for (int h = 0; h < 4; h++)
#pragma unroll
            for (int r = 0; r < 4; r++) {
              int s = s0 + h * 16 + g * 4 + r;
              bool ok = (s <= qq) && (s + WINDOW_ >= qq);
              float v = ok ? sacc[su][h][r] * CSC : -1e30f;
              sacc[su][h][r] = v;
              pm = fmaxf(pm, v);
            }
        }
        pm = fmaxf(pm, __shfl_xor(pm, 16));
        pm = fmaxf(pm, __shfl_xor(pm, 32));
        if (!__all(pm <= m_r[su] + 8.f)) {
          float mnew = fmaxf(m_r[su], pm);
          float alpha = exp2f(m_r[su] - mnew);
          m_r[su] = mnew;
          l_r[su] *= alpha;
          float aq[4];
#pragma unroll
          for (int r = 0; r < 4; r++) aq[r] = __shfl(alpha, g * 4 + r);
#pragma unroll
          for (int i = 0; i < 8; i++) {
            f32x4 e = eacc[su][i];
#pragma unroll
            for (int r = 0; r < 4; r++) e[r] *= aq[r];
            eacc[su][i] = e;
          }
        }
        float rs = 0.f;
#pragma unroll
        for (int h = 0; h < 4; h++)
#pragma unroll
          for (int r = 0; r < 4; r++) {
            float e = exp2f(sacc[su][h][r] - m_r[su]);
            sacc[su][h][r] = e;
            rs += e;
          }
        rs += __shfl_xor(rs, 16);
        rs += __shfl_xor(rs, 32);
        l_r[su] += rs;

        // P -> LDS (swizzled write), layout P[q=lr][s 0..63]
#pragma unroll
        for (int h = 0; h < 4; h++) {
          int base = (lr * 128 + h * 32 + g * 8) ^ swz;
          uint2 w2;
          w2.x = pack2bf(sacc[su][h][0], sacc[su][h][1]);
          w2.y = pack2bf(sacc[su][h][2], sacc[su][h][3]);
          *(uint2*)(Pw + su * 2048 + base) = w2;
        }
      }

      // ---- P frags + PV ----
      bf16x8 pf[2][2];
#pragma unroll
      for (int su = 0; su < 2; su++) {
        pf[su][0] = *(const bf16x8*)(Pw + su * 2048 + ((lr * 128 + g * 16) ^ swz));
        pf[su][1] = *(const bf16x8*)(Pw + su * 2048 + ((lr * 128 + 64 + g * 16) ^ swz));
      }
#pragma unroll
      for (int ht = 0; ht < 8; ht++) {
        const int vrow = ht * 16 + lr;
        bf16x8 vf0 = *(const bf16x8*)(vB + vrow * 128 + ((g * 16) ^ swz));
        bf16x8 vf1 = *(const bf16x8*)(vB + vrow * 128 + ((64 + g * 16) ^ swz));
#pragma unroll
        for (int su = 0; su < 2; su++) {
          eacc[su][ht] = mfma16(pf[su][0], vf0, eacc[su][ht]);
          eacc[su][ht] = mfma16(pf[su][1], vf1, eacc[su][ht]);
        }
      }
    }
    __syncthreads();
  }

  // ---- normalize + store ----
#pragma unroll
  for (int su = 0; su < 2; su++) {
    float lq[4];
#pragma unroll
    for (int r = 0; r < 4; r++) lq[r] = 1.f / __shfl(l_r[su], g * 4 + r);
#pragma unroll
    for (int ht = 0; ht < 8; ht++) {
#pragma unroll
      for (int r = 0; r < 4; r++) {
        int row = b * T_ + q0w + su * 16 + g * 4 + r;
        int col = n * HD_ + ht * 16 + lr;
        Eb[(size_t)row * WIDTH_ + col] = f2bf(eacc[su][ht][r] * lq[r]);
      }
    }
  }
}

// ---------------- launch ----------------
extern "C" void kernel_launch(void* const* d_in, const int* in_sizes, int n_in,
                              void* d_out, int out_size, void* d_ws, size_t ws_size,
                              hipStream_t stream) {
  (void)in_sizes; (void)n_in; (void)out_size; (void)ws_size;
  const float* x = (const float*)d_in[0];
  const int* segpos = (const int*)d_in[1];
  const float* wq = (const float*)d_in[3];
  const float* wk = (const float*)d_in[4];
  const float* wv = (const float*)d_in[5];
  const float* w_out = (const float*)d_in[6];
  const float* b_out = (const float*)d_in[7];

  char* p = (char*)d_ws;
  u16* xb = (u16*)p;   p += (size_t)MROWS_ * WIDTH_ * 2;
  u16* wqkv = (u16*)p; p += (size_t)NQKV_ * WIDTH_ * 2;
  u16* wob = (u16*)p;  p += (size_t)WIDTH_ * WIDTH_ * 2;
  u16* qkv = (u16*)p;  p += (size_t)MROWS_ * NQKV_ * 2;
  u16* qb = (u16*)p;   p += (size_t)MROWS_ * WIDTH_ * 2;
  u16* kb = (u16*)p;   p += (size_t)MROWS_ * HD_ * 2;
  u16* vt = (u16*)p;   p += (size_t)B_ * HD_ * T_ * 2;
  u16* eb = xb;  // alias: xb dead after QKV GEMM

  cvt_f32_bf16<<<4096, 256, 0, stream>>>(x, xb, MROWS_ * WIDTH_ / 4);
  cvt_f32_bf16<<<1024, 256, 0, stream>>>(wq, wqkv, WIDTH_ * WIDTH_ / 4);
  cvt_f32_bf16<<<256, 256, 0, stream>>>(wk, wqkv + (size_t)WIDTH_ * WIDTH_, HD_ * WIDTH_ / 4);
  cvt_f32_bf16<<<256, 256, 0, stream>>>(wv, wqkv + (size_t)(WIDTH_ + HD_) * WIDTH_, HD_ * WIDTH_ / 4);
  cvt_f32_bf16<<<1024, 256, 0, stream>>>(w_out, wob, WIDTH_ * WIDTH_ / 4);

  gemm_bt<false><<<dim3(NQKV_ / 128, MROWS_ / 128), 256, 0, stream>>>(
      xb, wqkv, qkv, nullptr, MROWS_, NQKV_, WIDTH_);
  rope_scatter<<<MROWS_, 256, 0, stream>>>(qkv, segpos, qb, kb, vt);
  attn<<<B_ * NHEADS_ * (T_ / 128), 256, 0, stream>>>(qb, kb, vt, eb);
  gemm_bt<true><<<dim3(WIDTH_ / 128, MROWS_ / 128), 256, 0, stream>>>(
      eb, wob, d_out, b_out, MROWS_, WIDTH_, WIDTH_);
}